// Round 13
// baseline (327.286 us; speedup 1.0000x reference)
//
#include <hip/hip_runtime.h>

// 3-layer LSTM (B=1024, T=512, H=64), f16 MFMA, fp32 cell state.
// grid = 256 blocks x 4 batches; 768 threads = 12 waves = 3 layer-teams x 4.
// R13 = R12 structure with a VALU-instruction diet (counters showed wall =
// MFMA-issue + VALU-issue serialized, VALU ~112 instr/wave/step):
//  1. x staged in LDS as ready-to-read A-fragments by 24 stager lanes spread
//     over team-0's 4 waves (6 lanes each): L0's per-step f32->f16 repack
//     (~14 VALU + selects) becomes ONE ds_read_b128.
//  2. single 3/4-deep MFMA chains with bias-as-C (no Z4 init movs, no adds).
//  3. kept from R10/R12: lgkm-only barrier (x global loads never drained),
//     exp2 interleaved into the MFMA region, hoisted parity addresses,
//     no setprio.
// mfma_f32_16x16x32_f16: A row = lane&15 (batch l15>>2, 4-way broadcast),
// k-chunk = lane>>4; D col = lane&15 (unit), D row = (lane>>4)*4+reg ->
// acc[tt][0] on lane (l4,l15) IS the preact of cell (batch=l4, unit=w*16+l15).
// Layout verified R2-R12.

typedef __attribute__((ext_vector_type(8))) _Float16 half8;
typedef __attribute__((ext_vector_type(4))) _Float16 half4;
typedef __attribute__((ext_vector_type(4))) float floatx4;

static constexpr int T_STEPS = 512;

#define NL2E  (-1.4426950408889634f)   // -log2(e)
#define N2L2E (-2.8853900817779268f)   // -2*log2(e)

// LDS map:
//  X   : [2 buf][4 bat][32 k] f16 = 2 x 256B   (k=24..31 zeroed once = pad)
//  H_L : [2 slot][4 bat][64 u] f16 = 2 x 512B per layer
//  addr_h = H_OFFL + slot*512 + ((bat*128 + unit*2) ^ ((bat&1)<<5))
#define XOFF     0
#define H_OFF0   512
#define H_OFF1   1536
#define H_OFF2   2560
#define SM_BYTES 3584

__device__ __forceinline__ floatx4 mfma16(half8 a, half8 b, floatx4 c) {
    return __builtin_amdgcn_mfma_f32_16x16x32_f16(a, b, c, 0, 0, 0);
}

__device__ __forceinline__ half8 cvt8s(const float* src, float s) {
    float4 v0 = *(const float4*)(src);
    float4 v1 = *(const float4*)(src + 4);
    half8 h;
    h[0] = (_Float16)(v0.x * s); h[1] = (_Float16)(v0.y * s);
    h[2] = (_Float16)(v0.z * s); h[3] = (_Float16)(v0.w * s);
    h[4] = (_Float16)(v1.x * s); h[5] = (_Float16)(v1.y * s);
    h[6] = (_Float16)(v1.z * s); h[7] = (_Float16)(v1.w * s);
    return h;
}

// h/x ds_writes visible to the block, WITHOUT draining vmcnt.
__device__ __forceinline__ void lds_barrier() {
    asm volatile("s_waitcnt lgkmcnt(0)" ::: "memory");
    __builtin_amdgcn_s_barrier();
}

__global__ __launch_bounds__(768, 3) void lstm3_v13(
    const float* __restrict__ x,
    const float* __restrict__ w_ih0, const float* __restrict__ w_hh0,
    const float* __restrict__ b_ih0, const float* __restrict__ b_hh0,
    const float* __restrict__ w_ih1, const float* __restrict__ w_hh1,
    const float* __restrict__ b_ih1, const float* __restrict__ b_hh1,
    const float* __restrict__ w_ih2, const float* __restrict__ w_hh2,
    const float* __restrict__ b_ih2, const float* __restrict__ b_hh2,
    const float* __restrict__ w_lin, const float* __restrict__ b_lin,
    float* __restrict__ out)
{
    __shared__ __align__(16) char sm[SM_BYTES];

    const int tid  = threadIdx.x;
    const int lane = tid & 63;
    const int wave = tid >> 6;       // 0..11
    const int L    = wave >> 2;      // layer team 0..2
    const int w    = wave & 3;       // wave within team (unit group)
    const int l15  = lane & 15;
    const int l4   = lane >> 4;      // k-chunk; also this lane's BATCH in D
    const int bat  = l15 >> 2;       // A-row's batch (broadcast pattern)
    const int b0   = blockIdx.x * 4;
    const int u    = w * 16 + l15;   // this lane's hidden unit

    // ---- zero LDS (x pad k=24..31 stays zero forever) ----
    for (int i = tid; i < SM_BYTES / 16; i += 768)
        *(floatx4*)(&sm[i * 16]) = floatx4{0.f, 0.f, 0.f, 0.f};

    // ---- per-team parameter pointers ----
    const float* wi = (L == 0) ? w_ih0 : (L == 1 ? w_ih1 : w_ih2);
    const float* wh = (L == 0) ? w_hh0 : (L == 1 ? w_hh1 : w_hh2);
    const float* bi = (L == 0) ? b_ih0 : (L == 1 ? b_ih1 : b_ih2);
    const float* bh = (L == 0) ? b_hh0 : (L == 1 ? b_hh1 : b_hh2);
    const int HB = (L == 0) ? H_OFF0 : (L == 1 ? H_OFF1 : H_OFF2);
    const int PB = (L == 1) ? H_OFF0 : H_OFF1;   // prev-layer region (L>=1)

    // ---- register-resident weights, PRE-SCALED by -log2e (g: -2log2e) ----
    half8 wf[4][4];
#pragma unroll
    for (int tt = 0; tt < 4; ++tt) {
        const int g = tt * 64 + u;
        const float sc = (tt == 2) ? N2L2E : NL2E;
        if (L == 0) {
            half8 z;
#pragma unroll
            for (int j = 0; j < 8; ++j) z[j] = (_Float16)0.f;
            wf[tt][0] = (l4 < 3) ? cvt8s(w_ih0 + g * 24 + l4 * 8, sc) : z;
            wf[tt][1] = cvt8s(w_hh0 + g * 64 + l4 * 8, sc);
            wf[tt][2] = cvt8s(w_hh0 + g * 64 + 32 + l4 * 8, sc);
            wf[tt][3] = z;
        } else {
            wf[tt][0] = cvt8s(wi + g * 64 + l4 * 8, sc);
            wf[tt][1] = cvt8s(wi + g * 64 + 32 + l4 * 8, sc);
            wf[tt][2] = cvt8s(wh + g * 64 + l4 * 8, sc);
            wf[tt][3] = cvt8s(wh + g * 64 + 32 + l4 * 8, sc);
        }
    }
    // scaled bias as MFMA C-input
    floatx4 bv[4];
#pragma unroll
    for (int tt = 0; tt < 4; ++tt) {
        const float sc = (tt == 2) ? N2L2E : NL2E;
        float b = sc * (bi[tt * 64 + u] + bh[tt * 64 + u]);
        bv[tt][0] = b; bv[tt][1] = b; bv[tt][2] = b; bv[tt][3] = b;
    }

    // ---- per-lane LDS byte addresses ----
    const int swzR = (bat & 1) << 5;
    int rb0 = 0, rb1 = 0, rb2 = 0, rb3 = 0;
    if (L == 0) {
        rb1 = H_OFF0 + ((bat * 128 + 0  + l4 * 16) ^ swzR);  // own h, units 0-31
        rb2 = H_OFF0 + ((bat * 128 + 64 + l4 * 16) ^ swzR);  // own h, units 32-63
    } else {
        rb0 = PB + ((bat * 128 + 0  + l4 * 16) ^ swzR);      // h_{L-1}(t)
        rb1 = PB + ((bat * 128 + 64 + l4 * 16) ^ swzR);
        rb2 = HB + ((bat * 128 + 0  + l4 * 16) ^ swzR);      // own h(t-1)
        rb3 = HB + ((bat * 128 + 64 + l4 * 16) ^ swzR);
    }
    const int wb = HB + ((l4 * 128 + u * 2) ^ ((l4 & 1) << 5));

    // x A-frag read addresses (chunk l4, batch bat), per buffer
    const int xr0 = XOFF + bat * 64 + l4 * 16;
    const int xr1 = xr0 + 256;

    // ---- hoisted per-parity h addresses. Even phase s: par = (s-L)&1 = L&1 ----
    const int par_e = L & 1;
    const int so_e = par_e * 512, sp_e = (par_e ^ 1) * 512;
    const int eA0 = rb0 + so_e;            // L>=1: prev h(t)
    const int eA1 = rb1 + ((L == 0) ? sp_e : so_e);
    const int eA2 = rb2 + sp_e;            // own h(t-1)
    const int eA3 = rb3 + sp_e;
    const int eWr = wb + so_e;
    const int oA0 = rb0 + sp_e;
    const int oA1 = rb1 + ((L == 0) ? so_e : sp_e);
    const int oA2 = rb2 + so_e;
    const int oA3 = rb3 + so_e;
    const int oWr = wb + sp_e;

    // ---- x stager: team-0 waves, lanes 0..5 (6 lanes x 4 waves = 24) ----
    // thread (wave w<4, lane xf<6) owns (batch w, float4 xf): k = xf*4..xf*4+3
    const bool stg = (L == 0) && (lane < 6);
    const int xf = lane;
    const int sxw0 = XOFF + 0   + w * 64 + xf * 8;   // write addr, buf 0
    const int sxw1 = XOFF + 256 + w * 64 + xf * 8;   // write addr, buf 1
    const float* xg = nullptr;
    if (stg) xg = x + ((long)(b0 + w) * T_STEPS + 1) * 24 + xf * 4;  // row t=1

    // stage x(0) -> buf 0 at setup
    if (stg) {
        float4 v = *(const float4*)(x + ((long)(b0 + w) * T_STEPS + 0) * 24 + xf * 4);
        half4 hv; hv[0] = (_Float16)v.x; hv[1] = (_Float16)v.y;
                  hv[2] = (_Float16)v.z; hv[3] = (_Float16)v.w;
        *(half4*)(&sm[sxw0]) = hv;
    }

    float cst = 0.0f;    // fp32 cell state of (batch l4, unit u, layer L)
    __syncthreads();     // setup visible (full drain, once)

    auto body = [&](int s, int A0, int A1, int A2, int A3, int WR,
                    int XR, int SXW) __attribute__((always_inline)) {
        const int t = s - L;
        const bool active = ((unsigned)t < (unsigned)T_STEPS);

        // stager: issue global load for x(s+1) early (consumed at body end)
        float4 xld;
        const bool do_x = stg && (s + 1 < T_STEPS);
        if (do_x) xld = *(const float4*)xg;

        if (active) {
            float e0, e1, e2, e3;
            if (L == 0) {
                half8 aX = *(const half8*)(&sm[XR]);
                half8 a1 = *(const half8*)(&sm[A1]);
                half8 a2 = *(const half8*)(&sm[A2]);
#pragma unroll
                for (int tt = 0; tt < 4; ++tt) {
                    floatx4 acc = mfma16(aX, wf[tt][0], bv[tt]);
                    acc = mfma16(a1, wf[tt][1], acc);
                    acc = mfma16(a2, wf[tt][2], acc);
                    float e = __builtin_amdgcn_exp2f(acc[0]);
                    if (tt == 0) e0 = e; else if (tt == 1) e1 = e;
                    else if (tt == 2) e2 = e; else e3 = e;
                }
            } else {
                half8 a0 = *(const half8*)(&sm[A0]);
                half8 a1 = *(const half8*)(&sm[A1]);
                half8 a2 = *(const half8*)(&sm[A2]);
                half8 a3 = *(const half8*)(&sm[A3]);
#pragma unroll
                for (int tt = 0; tt < 4; ++tt) {
                    floatx4 acc = mfma16(a0, wf[tt][0], bv[tt]);
                    acc = mfma16(a1, wf[tt][1], acc);
                    acc = mfma16(a2, wf[tt][2], acc);
                    acc = mfma16(a3, wf[tt][3], acc);
                    float e = __builtin_amdgcn_exp2f(acc[0]);
                    if (tt == 0) e0 = e; else if (tt == 1) e1 = e;
                    else if (tt == 2) e2 = e; else e3 = e;
                }
            }

            // combine tail: 4 rcp + cst + tanh + write
            float ig = __builtin_amdgcn_rcpf(1.f + e0);
            float fg = __builtin_amdgcn_rcpf(1.f + e1);
            float sg = __builtin_amdgcn_rcpf(1.f + e2);
            float og = __builtin_amdgcn_rcpf(1.f + e3);
            float gg = fmaf(2.f, sg, -1.f);                 // tanh(g)
            cst = fmaf(fg, cst, ig * gg);
            float et = __builtin_amdgcn_exp2f(cst * N2L2E);
            float th = fmaf(2.f, __builtin_amdgcn_rcpf(1.f + et), -1.f);
            float hv = og * th;
            *(_Float16*)(&sm[WR]) = (_Float16)hv;
        }

        // stager: commit x(s+1) as f16 A-frag data (load issued at body top)
        if (do_x) {
            half4 hv; hv[0] = (_Float16)xld.x; hv[1] = (_Float16)xld.y;
                      hv[2] = (_Float16)xld.z; hv[3] = (_Float16)xld.w;
            *(half4*)(&sm[SXW]) = hv;
            xg += 24;
        }
        lds_barrier();   // h(t), x(s+1) visible; vmcnt NOT drained
    };

    for (int s = 0; s < T_STEPS + 2; s += 2) {
        // even body: L0 reads x buf s&1=0 (xr0), stager writes buf 1 (sxw1)
        body(s,     eA0, eA1, eA2, eA3, eWr, xr0, sxw1);
        body(s + 1, oA0, oA1, oA2, oA3, oWr, xr1, sxw0);
    }

    __syncthreads();   // full drain before epilogue

    // ---- final linear: out[b,o] = h2(511) . w_lin[o,:] + b_lin[o] ----
    if (tid < 16) {
        const int bb = tid >> 2, o = tid & 3;
        const int sl = ((T_STEPS - 1) & 1) * 512;   // slot 1
        float accum = b_lin[o];
#pragma unroll
        for (int k = 0; k < 64; ++k) {
            const int off = H_OFF2 + sl + ((bb * 128 + k * 2) ^ ((bb & 1) << 5));
            accum = fmaf((float)*(const _Float16*)(&sm[off]), w_lin[o * 64 + k], accum);
        }
        out[(b0 + bb) * 4 + o] = accum;
    }
}

extern "C" void kernel_launch(void* const* d_in, const int* in_sizes, int n_in,
                              void* d_out, int out_size, void* d_ws, size_t ws_size,
                              hipStream_t stream) {
    const float* x     = (const float*)d_in[0];
    const float* w_ih0 = (const float*)d_in[1];
    const float* w_hh0 = (const float*)d_in[2];
    const float* b_ih0 = (const float*)d_in[3];
    const float* b_hh0 = (const float*)d_in[4];
    const float* w_ih1 = (const float*)d_in[5];
    const float* w_hh1 = (const float*)d_in[6];
    const float* b_ih1 = (const float*)d_in[7];
    const float* b_hh1 = (const float*)d_in[8];
    const float* w_ih2 = (const float*)d_in[9];
    const float* w_hh2 = (const float*)d_in[10];
    const float* b_ih2 = (const float*)d_in[11];
    const float* b_hh2 = (const float*)d_in[12];
    const float* w_lin = (const float*)d_in[13];
    const float* b_lin = (const float*)d_in[14];

    lstm3_v13<<<dim3(256), dim3(768), 0, stream>>>(
        x, w_ih0, w_hh0, b_ih0, b_hh0,
        w_ih1, w_hh1, b_ih1, b_hh1,
        w_ih2, w_hh2, b_ih2, b_hh2,
        w_lin, b_lin, (float*)d_out);
}

// Round 14
// 295.723 us; speedup vs baseline: 1.1067x; 1.1067x over previous
//
#include <hip/hip_runtime.h>

// 3-layer LSTM (B=1024, T=512, H=64), f16 MFMA, fp32 cell state.
// grid = 256 blocks x 4 batches; 768 threads = 12 waves = 3 layer-teams x 4.
// R14 = R6 (the measured champion, 301us) with ONE strictly-safe change:
// weights & biases pre-scaled by -log2e (g: -2log2e), removing the 4 serial
// v_mul from the activation critical path (verified identical absmax R9-R13).
//
// Team L computes layer L at t = s - L (skewed pipeline), ONE barrier/step.
// A-fragment reads use slot = l15>>2 (4-way same-address broadcast) so
// D-row 4*l4+r = batch l4: acc[tt][0] on lane (l4,l15) IS the preact of cell
// (batch=l4, unit=w*16+l15) -> activation fully lane-local.
// mfma_f32_16x16x32_f16: A row = lane&15, k-chunk = lane>>4; D col = lane&15,
// D row = (lane>>4)*4+reg -- layout verified R2-R13.
//
// Structural ceiling note (for the record): MFMA pipe floor ~853 cyc/SIMD-step
// (176 MFMAs/block-step, 4x M-waste forced by B_blk = B/num_CUs = 4 < 16);
// measured wall ~1400 cyc = floor + act-chain latency + issue serialization.
// Six scheduling variants (R7,R8,R10,R11,R12,R13) failed to compress it.

typedef __attribute__((ext_vector_type(8))) _Float16 half8;
typedef __attribute__((ext_vector_type(4))) _Float16 half4;
typedef __attribute__((ext_vector_type(4))) float floatx4;

static constexpr int T_STEPS = 512;

#define NL2E  (-1.4426950408889634f)   // -log2(e)
#define N2L2E (-2.8853900817779268f)   // -2*log2(e)

// LDS: "cr" rows of 256B = [16 slots][16B]; slot ^= (cr&1)<<2.
// CR_X  : [2 buf][4 chunks]  (x frags, k=0..31, 24 real + 8 zero pad)
// CR_Hl : [2 buf][8 chunks]  (h frags, 64 units); slots 0..3 = batches.
#define CR_X   0
#define CR_H0  8
#define CR_H1  24
#define CR_H2  40
#define CR_TOT 56
#define SM_BYTES (CR_TOT * 256)        // 14336 B

__device__ __forceinline__ int lds_off(int cr, int slot) {
    return (cr * 16 + (slot ^ ((cr & 1) << 2))) * 16;
}

__device__ __forceinline__ floatx4 mfma16(half8 a, half8 b, floatx4 c) {
    return __builtin_amdgcn_mfma_f32_16x16x32_f16(a, b, c, 0, 0, 0);
}

__device__ __forceinline__ half8 cvt8s(const float* src, float s) {
    float4 v0 = *(const float4*)(src);
    float4 v1 = *(const float4*)(src + 4);
    half8 h;
    h[0] = (_Float16)(v0.x * s); h[1] = (_Float16)(v0.y * s);
    h[2] = (_Float16)(v0.z * s); h[3] = (_Float16)(v0.w * s);
    h[4] = (_Float16)(v1.x * s); h[5] = (_Float16)(v1.y * s);
    h[6] = (_Float16)(v1.z * s); h[7] = (_Float16)(v1.w * s);
    return h;
}

__global__ __launch_bounds__(768, 3) void lstm3_v14(
    const float* __restrict__ x,
    const float* __restrict__ w_ih0, const float* __restrict__ w_hh0,
    const float* __restrict__ b_ih0, const float* __restrict__ b_hh0,
    const float* __restrict__ w_ih1, const float* __restrict__ w_hh1,
    const float* __restrict__ b_ih1, const float* __restrict__ b_hh1,
    const float* __restrict__ w_ih2, const float* __restrict__ w_hh2,
    const float* __restrict__ b_ih2, const float* __restrict__ b_hh2,
    const float* __restrict__ w_lin, const float* __restrict__ b_lin,
    float* __restrict__ out)
{
    __shared__ __align__(16) char sm[SM_BYTES];

    const int tid  = threadIdx.x;
    const int lane = tid & 63;
    const int wave = tid >> 6;       // 0..11
    const int L    = wave >> 2;      // layer team 0..2
    const int w    = wave & 3;       // unit group within team
    const int l15  = lane & 15;
    const int l4   = lane >> 4;      // = this lane's BATCH
    const int b0   = blockIdx.x * 4; // global batch base (4 per block)
    const int u    = w * 16 + l15;   // this lane's hidden unit
    const int sl   = l15 >> 2;       // broadcast A slot

    // ---- zero x + h frag regions ----
    for (int i = tid; i < CR_TOT * 16; i += 768)
        *(floatx4*)(&sm[i * 16]) = floatx4{0.f, 0.f, 0.f, 0.f};

    // ---- per-team parameter pointers ----
    const float* wi = (L == 0) ? w_ih0 : (L == 1 ? w_ih1 : w_ih2);
    const float* wh = (L == 0) ? w_hh0 : (L == 1 ? w_hh1 : w_hh2);
    const float* bi = (L == 0) ? b_ih0 : (L == 1 ? b_ih1 : b_ih2);
    const float* bh = (L == 0) ? b_hh0 : (L == 1 ? b_hh1 : b_hh2);
    const int hbase = (L == 0) ? CR_H0 : (L == 1 ? CR_H1 : CR_H2);
    const int pbase = (L == 0) ? CR_X  : (L == 1 ? CR_H0 : CR_H1);

    // ---- register-resident B frags (weights), PRE-SCALED by -log2e ----
    half8 wf[4][4];
#pragma unroll
    for (int tt = 0; tt < 4; ++tt) {
        const int g = tt * 64 + u;
        const float sc = (tt == 2) ? N2L2E : NL2E;
        if (L == 0) {
            half8 z;
#pragma unroll
            for (int j = 0; j < 8; ++j) z[j] = (_Float16)0.f;
            wf[tt][0] = (l4 < 3) ? cvt8s(w_ih0 + g * 24 + l4 * 8, sc) : z;
            wf[tt][1] = cvt8s(w_hh0 + g * 64 + l4 * 8, sc);
            wf[tt][2] = cvt8s(w_hh0 + g * 64 + 32 + l4 * 8, sc);
            wf[tt][3] = z;   // unused
        } else {
            wf[tt][0] = cvt8s(wi + g * 64 + l4 * 8, sc);
            wf[tt][1] = cvt8s(wi + g * 64 + 32 + l4 * 8, sc);
            wf[tt][2] = cvt8s(wh + g * 64 + l4 * 8, sc);
            wf[tt][3] = cvt8s(wh + g * 64 + 32 + l4 * 8, sc);
        }
    }

    // ---- pre-scaled bias as MFMA C-input (same for all 4 acc rows) ----
    floatx4 bv[4];
#pragma unroll
    for (int tt = 0; tt < 4; ++tt) {
        const float sc = (tt == 2) ? N2L2E : NL2E;
        float b = sc * (bi[tt * 64 + u] + bh[tt * 64 + u]);
        bv[tt][0] = b; bv[tt][1] = b; bv[tt][2] = b; bv[tt][3] = b;
    }
    float cst = 0.0f;    // fp32 cell state of (batch l4, unit u, layer L)

    // ---- precomputed LDS byte addresses, both parities ----
    int ra0[4], ra1[4];
    if (L == 0) {
        ra0[0] = lds_off(CR_X + 0 + l4, sl);
        ra0[1] = lds_off(CR_H0 + 8 + l4, sl);
        ra0[2] = lds_off(CR_H0 + 12 + l4, sl);
        ra0[3] = 0;
        ra1[0] = lds_off(CR_X + 4 + l4, sl);
        ra1[1] = lds_off(CR_H0 + 0 + l4, sl);
        ra1[2] = lds_off(CR_H0 + 4 + l4, sl);
        ra1[3] = 0;
    } else {
        ra0[0] = lds_off(pbase + 0 + l4, sl);
        ra0[1] = lds_off(pbase + 4 + l4, sl);
        ra0[2] = lds_off(hbase + 8 + l4, sl);
        ra0[3] = lds_off(hbase + 12 + l4, sl);
        ra1[0] = lds_off(pbase + 8 + l4, sl);
        ra1[1] = lds_off(pbase + 12 + l4, sl);
        ra1[2] = lds_off(hbase + 0 + l4, sl);
        ra1[3] = lds_off(hbase + 4 + l4, sl);
    }
    const int wr0 = lds_off(hbase + 0 + (u >> 3), l4) + (u & 7) * 2;
    const int wr1 = lds_off(hbase + 8 + (u >> 3), l4) + (u & 7) * 2;

    // parity selects (loop-invariant, hoisted): even-s body has par = L&1
    const int Lodd = L & 1;
    const int eA0 = Lodd ? ra1[0] : ra0[0], eA1 = Lodd ? ra1[1] : ra0[1];
    const int eA2 = Lodd ? ra1[2] : ra0[2], eA3 = Lodd ? ra1[3] : ra0[3];
    const int oA0 = Lodd ? ra0[0] : ra1[0], oA1 = Lodd ? ra0[1] : ra1[1];
    const int oA2 = Lodd ? ra0[2] : ra1[2], oA3 = Lodd ? ra0[3] : ra1[3];
    const int eWr = Lodd ? wr1 : wr0, oWr = Lodd ? wr0 : wr1;

    // ---- x staging: thread tid<24 owns (batch xb, float4 xf) ----
    const int xb = tid / 6, xf = tid % 6;
    const int xw0 = lds_off(CR_X + 0 + (xf >> 1), xb) + (xf & 1) * 8;
    const int xw1 = lds_off(CR_X + 4 + (xf >> 1), xb) + (xf & 1) * 8;
    const float* xg = x + ((long)(b0 + xb) * T_STEPS + 1) * 24 + xf * 4;
    if (tid < 24) {
        float4 v = *(const float4*)(x + ((long)(b0 + xb) * T_STEPS + 0) * 24 + xf * 4);
        half4 hv; hv[0] = (_Float16)v.x; hv[1] = (_Float16)v.y;
                  hv[2] = (_Float16)v.z; hv[3] = (_Float16)v.w;
        *(half4*)(&sm[xw0]) = hv;
    }
    __syncthreads();

    auto body = [&](int s, int A0, int A1, int A2, int A3, int WR, int XW) {
        const int t = s - L;
        const bool active = ((unsigned)t < (unsigned)T_STEPS);
        float4 xpre;
        const bool do_x = (tid < 24) && (s + 1 < T_STEPS);
        if (do_x) xpre = *(const float4*)xg;

        if (active) {
            floatx4 acc[4];
            __builtin_amdgcn_s_setprio(1);
            if (L == 0) {
                half8 aX  = *(const half8*)(&sm[A0]);
                half8 aP0 = *(const half8*)(&sm[A1]);
                half8 aP1 = *(const half8*)(&sm[A2]);
#pragma unroll
                for (int tt = 0; tt < 4; ++tt) {
                    acc[tt] = mfma16(aX,  wf[tt][0], bv[tt]);
                    acc[tt] = mfma16(aP0, wf[tt][1], acc[tt]);
                    acc[tt] = mfma16(aP1, wf[tt][2], acc[tt]);
                }
            } else {
                half8 aI0 = *(const half8*)(&sm[A0]);
                half8 aI1 = *(const half8*)(&sm[A1]);
                half8 aO0 = *(const half8*)(&sm[A2]);
                half8 aO1 = *(const half8*)(&sm[A3]);
#pragma unroll
                for (int tt = 0; tt < 4; ++tt) {
                    acc[tt] = mfma16(aI0, wf[tt][0], bv[tt]);
                    acc[tt] = mfma16(aI1, wf[tt][1], acc[tt]);
                    acc[tt] = mfma16(aO0, wf[tt][2], acc[tt]);
                    acc[tt] = mfma16(aO1, wf[tt][3], acc[tt]);
                }
            }
            __builtin_amdgcn_s_setprio(0);

            // activation: 1 cell/lane; acc = -(preact)*log2e (g: -2log2e)
            float ei = __builtin_amdgcn_exp2f(acc[0][0]);
            float ef = __builtin_amdgcn_exp2f(acc[1][0]);
            float eg = __builtin_amdgcn_exp2f(acc[2][0]);
            float eo = __builtin_amdgcn_exp2f(acc[3][0]);
            float ig = __builtin_amdgcn_rcpf(1.f + ei);
            float fg = __builtin_amdgcn_rcpf(1.f + ef);
            float sg = __builtin_amdgcn_rcpf(1.f + eg);
            float og = __builtin_amdgcn_rcpf(1.f + eo);
            float gg = fmaf(2.f, sg, -1.f);                 // tanh(g)
            cst = fmaf(fg, cst, ig * gg);
            float et = __builtin_amdgcn_exp2f(cst * N2L2E);
            float th = fmaf(2.f, __builtin_amdgcn_rcpf(1.f + et), -1.f);
            float hv = og * th;
            *(_Float16*)(&sm[WR]) = (_Float16)hv;
        }
        if (do_x) {
            half4 hv; hv[0] = (_Float16)xpre.x; hv[1] = (_Float16)xpre.y;
                      hv[2] = (_Float16)xpre.z; hv[3] = (_Float16)xpre.w;
            *(half4*)(&sm[XW]) = hv;
        }
        xg += 24;
        __syncthreads();
    };

    for (int s = 0; s < T_STEPS + 2; s += 2) {
        body(s,     eA0, eA1, eA2, eA3, eWr, xw1);   // writes x(s+1) -> buf 1
        body(s + 1, oA0, oA1, oA2, oA3, oWr, xw0);   // writes x(s+2) -> buf 0
    }

    // ---- final linear: out[b,o] = h2(511) . w_lin[o,:] + b_lin[o] ----
    if (tid < 16) {
        const int bb = tid >> 2, o = tid & 3;
        const int hb = CR_H2 + ((T_STEPS - 1) & 1) * 8;
        float acc = b_lin[o];
#pragma unroll
        for (int k = 0; k < 64; ++k) {
            _Float16 hv = *(const _Float16*)(&sm[lds_off(hb + (k >> 3), bb) + (k & 7) * 2]);
            acc = fmaf((float)hv, w_lin[o * 64 + k], acc);
        }
        out[(b0 + bb) * 4 + o] = acc;
    }
}

extern "C" void kernel_launch(void* const* d_in, const int* in_sizes, int n_in,
                              void* d_out, int out_size, void* d_ws, size_t ws_size,
                              hipStream_t stream) {
    const float* x     = (const float*)d_in[0];
    const float* w_ih0 = (const float*)d_in[1];
    const float* w_hh0 = (const float*)d_in[2];
    const float* b_ih0 = (const float*)d_in[3];
    const float* b_hh0 = (const float*)d_in[4];
    const float* w_ih1 = (const float*)d_in[5];
    const float* w_hh1 = (const float*)d_in[6];
    const float* b_ih1 = (const float*)d_in[7];
    const float* b_hh1 = (const float*)d_in[8];
    const float* w_ih2 = (const float*)d_in[9];
    const float* w_hh2 = (const float*)d_in[10];
    const float* b_ih2 = (const float*)d_in[11];
    const float* b_hh2 = (const float*)d_in[12];
    const float* w_lin = (const float*)d_in[13];
    const float* b_lin = (const float*)d_in[14];

    lstm3_v14<<<dim3(256), dim3(768), 0, stream>>>(
        x, w_ih0, w_hh0, b_ih0, b_hh0,
        w_ih1, w_hh1, b_ih1, b_hh1,
        w_ih2, w_hh2, b_ih2, b_hh2,
        w_lin, b_lin, (float*)d_out);
}